// Round 1
// baseline (202.068 us; speedup 1.0000x reference)
//
#include <hip/hip_runtime.h>
#include <math.h>

#define NEG_BIG (-9.0e15f)

// ---------------- CNN: per-instance 1->16->32 convs on 9x9 ----------------
__global__ __launch_bounds__(256) void cnn_kernel(
    const float* __restrict__ obs, const float* __restrict__ w1,
    const float* __restrict__ b1, const float* __restrict__ w2,
    const float* __restrict__ b2, float* __restrict__ feats)
{
  const int IPB = 8;
  __shared__ float sw1[144];
  __shared__ float sb1[16];
  __shared__ float sb2[32];
  __shared__ float sw2[32 * 145];      // padded stride 145 (kills 16-way conflict)
  __shared__ float sin_[IPB][81];
  __shared__ float sh1[IPB][16 * 81];
  int tid = threadIdx.x;
  long inst0 = (long)blockIdx.x * IPB;

  for (int i = tid; i < 144; i += 256) sw1[i] = w1[i];
  if (tid < 16) sb1[tid] = b1[tid];
  if (tid < 32) sb2[tid] = b2[tid];
  for (int i = tid; i < 32 * 144; i += 256) sw2[(i / 144) * 145 + (i % 144)] = w2[i];
  for (int i = tid; i < IPB * 81; i += 256) sin_[i / 81][i % 81] = obs[inst0 * 81 + i];
  __syncthreads();

  // conv1 (SAME, 3x3, 1->16) + ReLU
  for (int idx = tid; idx < IPB * 16 * 81; idx += 256) {
    int inst = idx / 1296; int r = idx % 1296; int c = r / 81; int pp = r % 81;
    int y = pp / 9, x = pp % 9;
    float acc = sb1[c];
    #pragma unroll
    for (int ky = 0; ky < 3; ++ky) {
      int yy = y + ky - 1;
      #pragma unroll
      for (int kx = 0; kx < 3; ++kx) {
        int xx = x + kx - 1;
        if (yy >= 0 && yy <= 8 && xx >= 0 && xx <= 8)
          acc += sin_[inst][yy * 9 + xx] * sw1[c * 9 + ky * 3 + kx];
      }
    }
    sh1[inst][c * 81 + pp] = fmaxf(acc, 0.0f);
  }
  __syncthreads();

  // conv2 (VALID, 3x3, 16->32) + ReLU: one (inst, o) per thread, register tiled
  int inst = tid >> 5, o = tid & 31;
  float acc[49];
  float bias = sb2[o];
  #pragma unroll
  for (int i = 0; i < 49; ++i) acc[i] = bias;
  const float* wb = &sw2[o * 145];
  const float* hb0 = &sh1[inst][0];
  for (int ci = 0; ci < 16; ++ci) {
    float wv[9];
    #pragma unroll
    for (int k = 0; k < 9; ++k) wv[k] = wb[ci * 9 + k];
    const float* hb = hb0 + ci * 81;
    float r0[9], r1[9], r2[9];
    #pragma unroll
    for (int k = 0; k < 9; ++k) { r0[k] = hb[k]; r1[k] = hb[9 + k]; }
    #pragma unroll
    for (int y = 0; y < 7; ++y) {
      #pragma unroll
      for (int k = 0; k < 9; ++k) r2[k] = hb[(y + 2) * 9 + k];
      #pragma unroll
      for (int x = 0; x < 7; ++x) {
        acc[y * 7 + x] += r0[x] * wv[0] + r0[x + 1] * wv[1] + r0[x + 2] * wv[2]
                        + r1[x] * wv[3] + r1[x + 1] * wv[4] + r1[x + 2] * wv[5]
                        + r2[x] * wv[6] + r2[x + 1] * wv[7] + r2[x + 2] * wv[8];
      }
      #pragma unroll
      for (int k = 0; k < 9; ++k) { r0[k] = r1[k]; r1[k] = r2[k]; }
    }
  }
  float* fb = feats + (inst0 + inst) * 1568 + o * 49;
  #pragma unroll
  for (int i = 0; i < 49; ++i) fb[i] = fmaxf(acc[i], 0.0f);
}

// ---------------- GEMM: Wh = feats(8192x1568) @ W(1568x64) ----------------
__global__ __launch_bounds__(256) void gemm_wh(
    const float* __restrict__ A, const float* __restrict__ B,
    float* __restrict__ C)
{
  __shared__ float As[32][33];
  __shared__ __align__(16) float Bs[32][64];
  int tid = threadIdx.x;
  long m0 = (long)blockIdx.x * 32;
  int tr = tid >> 4, tc = tid & 15;
  float acc[2][4] = {{0, 0, 0, 0}, {0, 0, 0, 0}};
  int ar = tid >> 3, ac = (tid & 7) * 4;
  int br = tid >> 4, bc = (tid & 15) * 4;
  for (int k0 = 0; k0 < 1568; k0 += 32) {
    float4 av = *(const float4*)&A[(m0 + ar) * 1568 + k0 + ac];
    As[ar][ac] = av.x; As[ar][ac + 1] = av.y; As[ar][ac + 2] = av.z; As[ar][ac + 3] = av.w;
    *(float4*)&Bs[br][bc] = *(const float4*)&B[(k0 + br) * 64 + bc];
    *(float4*)&Bs[br + 16][bc] = *(const float4*)&B[(k0 + br + 16) * 64 + bc];
    __syncthreads();
    #pragma unroll
    for (int k = 0; k < 32; ++k) {
      float a0 = As[tr * 2][k], a1 = As[tr * 2 + 1][k];
      float4 bv = *(const float4*)&Bs[k][tc * 4];
      acc[0][0] += a0 * bv.x; acc[0][1] += a0 * bv.y; acc[0][2] += a0 * bv.z; acc[0][3] += a0 * bv.w;
      acc[1][0] += a1 * bv.x; acc[1][1] += a1 * bv.y; acc[1][2] += a1 * bv.z; acc[1][3] += a1 * bv.w;
    }
    __syncthreads();
  }
  float4 o0 = {acc[0][0], acc[0][1], acc[0][2], acc[0][3]};
  float4 o1 = {acc[1][0], acc[1][1], acc[1][2], acc[1][3]};
  *(float4*)&C[(m0 + tr * 2) * 64 + tc * 4] = o0;
  *(float4*)&C[(m0 + tr * 2 + 1) * 64 + tc * 4] = o1;
}

// ---------------- s1/s2: row dots of Wh with a1,a2 ----------------
__global__ __launch_bounds__(256) void s12_kernel(
    const float* __restrict__ Wh, const float* __restrict__ a1,
    const float* __restrict__ a2, float* __restrict__ s1, float* __restrict__ s2)
{
  __shared__ float sa1[64], sa2[64];
  int tid = threadIdx.x;
  if (tid < 64) { sa1[tid] = a1[tid]; sa2[tid] = a2[tid]; }
  __syncthreads();
  long i = (long)blockIdx.x * 256 + tid;
  const float* row = Wh + i * 64;
  float x1 = 0.f, x2 = 0.f;
  #pragma unroll
  for (int d0 = 0; d0 < 64; d0 += 4) {
    float4 v = *(const float4*)&row[d0];
    x1 += v.x * sa1[d0] + v.y * sa1[d0 + 1] + v.z * sa1[d0 + 2] + v.w * sa1[d0 + 3];
    x2 += v.x * sa2[d0] + v.y * sa2[d0 + 1] + v.z * sa2[d0 + 2] + v.w * sa2[d0 + 3];
  }
  s1[i] = x1; s2[i] = x2;
}

// ---------------- GAT: masked softmax + attn@Wh + ELU + heads ----------------
#define PSTR 1028
__global__ __launch_bounds__(256) void gat_kernel(
    const int* __restrict__ adj, const float* __restrict__ Wh,
    const float* __restrict__ s1, const float* __restrict__ s2,
    const float* __restrict__ actor_w, const float* __restrict__ actor_b,
    const float* __restrict__ critic_w, const float* __restrict__ critic_b,
    float* __restrict__ out)
{
  __shared__ __align__(16) float p[16 * PSTR];   // scores -> probs (unnormalized)
  __shared__ float s2s[1024];
  __shared__ float saw[64 * 16];
  __shared__ float scw[64];
  __shared__ float sab[16];
  __shared__ float denom[16];
  __shared__ float emb[16][65];
  int tid = threadIdx.x;
  int b = blockIdx.y;
  int i0 = blockIdx.x * 16;

  for (int j = tid; j < 1024; j += 256) s2s[j] = s2[b * 1024 + j];
  for (int idx2 = tid; idx2 < 64 * 16; idx2 += 256) saw[idx2] = actor_w[idx2];
  if (tid < 64) scw[tid] = critic_w[tid];
  if (tid < 16) sab[tid] = actor_b[tid];
  __syncthreads();

  // Phase A: masked leaky-relu scores + online-free 2-pass softmax (16 lanes/row)
  {
    int il = tid >> 4, r = tid & 15;
    int i = i0 + il;
    float s1i = s1[b * 1024 + i];
    const int* arow = adj + ((long)(b * 1024 + i)) * 1024;
    float* prow = &p[il * PSTR];
    float m = -3.0e38f;
    for (int jj = 0; jj < 64; ++jj) {
      int j = r + jj * 16;
      int a = arow[j];
      float s = s1i + s2s[j];
      float e = (s > 0.f) ? s : 0.2f * s;
      e = (a > 0) ? e : NEG_BIG;
      prow[j] = e;
      m = fmaxf(m, e);
    }
    #pragma unroll
    for (int w = 1; w < 16; w <<= 1) m = fmaxf(m, __shfl_xor(m, w));
    float sum = 0.f;
    for (int jj = 0; jj < 64; ++jj) {
      int j = r + jj * 16;
      float pe = __expf(prow[j] - m);
      prow[j] = pe;
      sum += pe;
    }
    #pragma unroll
    for (int w = 1; w < 16; w <<= 1) sum += __shfl_xor(sum, w);
    if (r == 0) denom[il] = sum;
  }
  __syncthreads();

  // Phase B: h' = p @ Wh  (16x1024 @ 1024x64), 4x4 register tile per thread
  int g = tid >> 6, sub = tid & 63, ti = sub >> 4, td = sub & 15;
  float acc[4][4] = {};
  const float* WhB = Wh + ((long)b * 1024) * 64;
  int k0 = g * 256;
  for (int k = k0; k < k0 + 256; k += 4) {
    float4 a4[4];
    #pragma unroll
    for (int ii = 0; ii < 4; ++ii) a4[ii] = *(const float4*)&p[(ti * 4 + ii) * PSTR + k];
    #pragma unroll
    for (int kk = 0; kk < 4; ++kk) {
      float4 wv = *(const float4*)&WhB[(k + kk) * 64 + td * 4];
      #pragma unroll
      for (int ii = 0; ii < 4; ++ii) {
        float av = (kk == 0) ? a4[ii].x : (kk == 1) ? a4[ii].y : (kk == 2) ? a4[ii].z : a4[ii].w;
        acc[ii][0] += av * wv.x; acc[ii][1] += av * wv.y;
        acc[ii][2] += av * wv.z; acc[ii][3] += av * wv.w;
      }
    }
  }
  __syncthreads();            // all reads of p done -> safe to overlay
  float* red = p;             // [4 groups][16 rows][64 dims]
  #pragma unroll
  for (int ii = 0; ii < 4; ++ii) {
    float4 v = {acc[ii][0], acc[ii][1], acc[ii][2], acc[ii][3]};
    *(float4*)&red[(g * 16 + ti * 4 + ii) * 64 + td * 4] = v;
  }
  __syncthreads();

  // cross-group reduce + normalize + ELU
  #pragma unroll
  for (int qq = 0; qq < 4; ++qq) {
    int q = tid + qq * 256;
    int il = q >> 6, d = q & 63;
    float v = red[il * 64 + d] + red[(16 + il) * 64 + d]
            + red[(32 + il) * 64 + d] + red[(48 + il) * 64 + d];
    v /= denom[il];
    v = (v > 0.f) ? v : expm1f(v);
    emb[il][d] = v;
  }
  __syncthreads();

  // heads
  {
    int il = tid >> 4, na = tid & 15;
    float accl = sab[na];
    #pragma unroll
    for (int d = 0; d < 64; ++d) accl += emb[il][d] * saw[d * 16 + na];
    out[((long)(b * 1024 + i0 + il)) * 16 + na] = accl;
  }
  if (tid < 16) {
    float v = critic_b[0];
    #pragma unroll
    for (int d = 0; d < 64; ++d) v += emb[tid][d] * scw[d];
    out[131072 + b * 1024 + i0 + tid] = v;
  }
}

extern "C" void kernel_launch(void* const* d_in, const int* in_sizes, int n_in,
                              void* d_out, int out_size, void* d_ws, size_t ws_size,
                              hipStream_t stream)
{
  const float* obs = (const float*)d_in[0];
  const int*   adj = (const int*)d_in[1];
  const float* c1w = (const float*)d_in[2];
  const float* c1b = (const float*)d_in[3];
  const float* c2w = (const float*)d_in[4];
  const float* c2b = (const float*)d_in[5];
  const float* W   = (const float*)d_in[6];
  const float* a1  = (const float*)d_in[7];
  const float* a2  = (const float*)d_in[8];
  const float* aw  = (const float*)d_in[9];
  const float* ab  = (const float*)d_in[10];
  const float* cw  = (const float*)d_in[11];
  const float* cb  = (const float*)d_in[12];
  float* out = (float*)d_out;
  float* ws = (float*)d_ws;

  float* feats = ws;                              // 8192*1568 = 12,845,056 f32
  float* Wh    = ws + 12845056;                   // 8192*64   = 524,288 f32
  float* s1    = ws + 12845056 + 524288;          // 8192 f32
  float* s2    = s1 + 8192;                       // 8192 f32  (total ~53.5 MB)

  hipLaunchKernelGGL(cnn_kernel, dim3(1024), dim3(256), 0, stream,
                     obs, c1w, c1b, c2w, c2b, feats);
  hipLaunchKernelGGL(gemm_wh, dim3(256), dim3(256), 0, stream, feats, W, Wh);
  hipLaunchKernelGGL(s12_kernel, dim3(32), dim3(256), 0, stream, Wh, a1, a2, s1, s2);
  hipLaunchKernelGGL(gat_kernel, dim3(64, 8), dim3(256), 0, stream,
                     adj, Wh, s1, s2, aw, ab, cw, cb, out);
}

// Round 2
// 173.642 us; speedup vs baseline: 1.1637x; 1.1637x over previous
//
#include <hip/hip_runtime.h>
#include <math.h>

#define NEG_BIG (-9.0e15f)

// ---------------- CNN: per-instance 1->16->32 convs on 9x9 ----------------
// 8 instances/block. conv2 accumulates over 4 groups of 4 input channels so
// the h1 staging buffer is 1/4 size -> 34KB LDS total -> 4 blocks/CU.
#define IPB 8
__global__ __launch_bounds__(256) void cnn_kernel(
    const float* __restrict__ obs, const float* __restrict__ w1,
    const float* __restrict__ b1, const float* __restrict__ w2,
    const float* __restrict__ b2, float* __restrict__ feats)
{
  __shared__ float sw1[144];
  __shared__ float sb1[16];
  __shared__ float sb2[32];
  __shared__ float sw2t[144 * 33];     // [ci*9+k][o], stride 33 (conflict-free)
  __shared__ float sinp[IPB * 121];    // zero-padded 11x11 per instance
  __shared__ float sh1[IPB * 4 * 81];  // one 4-channel group of h1
  int tid = threadIdx.x;
  long inst0 = (long)blockIdx.x * IPB;

  for (int i = tid; i < 144; i += 256) sw1[i] = w1[i];
  if (tid < 16) sb1[tid] = b1[tid];
  if (tid < 32) sb2[tid] = b2[tid];
  // coalesced global read of w2, transposed scatter into LDS (stride 33)
  for (int i = tid; i < 4608; i += 256) {
    int o = i / 144, r = i - o * 144;
    sw2t[r * 33 + o] = w2[i];
  }
  // zero-padded input: padded coords (py,px) in 11x11, interior = obs
  for (int i = tid; i < IPB * 121; i += 256) {
    int inst = i / 121, rem = i - inst * 121;
    int py = rem / 11, px = rem - py * 11;
    float v = 0.f;
    if (py >= 1 && py <= 9 && px >= 1 && px <= 9)
      v = obs[(inst0 + inst) * 81 + (py - 1) * 9 + (px - 1)];
    sinp[inst * 121 + rem] = v;
  }
  __syncthreads();

  int inst = tid >> 5, o = tid & 31;   // conv2 role: one (inst, out-ch) per thread
  float acc[49];
  float bias2 = sb2[o];
  #pragma unroll
  for (int i = 0; i < 49; ++i) acc[i] = bias2;
  const float* sin_b = &sinp[inst * 121];
  const float* hb0 = &sh1[inst * 324];

  for (int g = 0; g < 4; ++g) {
    // ---- conv1 for channels 4g..4g+3 (SAME, no branches: padded input) ----
    {
      int ci1 = tid >> 5, s = tid & 31;       // reuse (inst, s) mapping
      const float* ib = &sinp[ci1 * 121];
      for (int cl = 0; cl < 4; ++cl) {
        int c = g * 4 + cl;
        float wk[9];
        #pragma unroll
        for (int k = 0; k < 9; ++k) wk[k] = sw1[c * 9 + k];
        float bias = sb1[c];
        #pragma unroll
        for (int t = 0; t < 3; ++t) {
          int px = s + t * 32;
          if (px < 81) {
            int y = (px * 456) >> 12;         // px/9 for px<81
            const float* ip = ib + px + 2 * y; // = y*11 + x (padded base)
            float a = bias
              + ip[0]  * wk[0] + ip[1]  * wk[1] + ip[2]  * wk[2]
              + ip[11] * wk[3] + ip[12] * wk[4] + ip[13] * wk[5]
              + ip[22] * wk[6] + ip[23] * wk[7] + ip[24] * wk[8];
            sh1[(ci1 * 4 + cl) * 81 + px] = fmaxf(a, 0.f);
          }
        }
      }
    }
    __syncthreads();

    // ---- conv2 partial: accumulate 4 input channels (VALID 7x7) ----
    for (int cl = 0; cl < 4; ++cl) {
      float wv[9];
      #pragma unroll
      for (int k = 0; k < 9; ++k) wv[k] = sw2t[((g * 4 + cl) * 9 + k) * 33 + o];
      const float* hb = hb0 + cl * 81;
      float r0[9], r1[9], r2[9];
      #pragma unroll
      for (int k = 0; k < 9; ++k) { r0[k] = hb[k]; r1[k] = hb[9 + k]; }
      #pragma unroll
      for (int y = 0; y < 7; ++y) {
        #pragma unroll
        for (int k = 0; k < 9; ++k) r2[k] = hb[(y + 2) * 9 + k];
        #pragma unroll
        for (int x = 0; x < 7; ++x) {
          acc[y * 7 + x] += r0[x] * wv[0] + r0[x + 1] * wv[1] + r0[x + 2] * wv[2]
                          + r1[x] * wv[3] + r1[x + 1] * wv[4] + r1[x + 2] * wv[5]
                          + r2[x] * wv[6] + r2[x + 1] * wv[7] + r2[x + 2] * wv[8];
        }
        #pragma unroll
        for (int k = 0; k < 9; ++k) { r0[k] = r1[k]; r1[k] = r2[k]; }
      }
    }
    __syncthreads();   // before next group overwrites sh1
  }

  float* fb = feats + (inst0 + inst) * 1568 + o * 49;
  #pragma unroll
  for (int i = 0; i < 49; ++i) fb[i] = fmaxf(acc[i], 0.0f);
}

// ------- GEMM: Wh = feats(8192x1568) @ W(1568x64), fused s1/s2 epilogue -------
__global__ __launch_bounds__(256) void gemm_wh(
    const float* __restrict__ A, const float* __restrict__ B,
    const float* __restrict__ a1, const float* __restrict__ a2,
    float* __restrict__ C, float* __restrict__ s1, float* __restrict__ s2)
{
  __shared__ float As[32][33];
  __shared__ __align__(16) float Bs[32][64];
  int tid = threadIdx.x;
  long m0 = (long)blockIdx.x * 32;
  int tr = tid >> 4, tc = tid & 15;
  float acc[2][4] = {{0, 0, 0, 0}, {0, 0, 0, 0}};
  int ar = tid >> 3, ac = (tid & 7) * 4;
  int br = tid >> 4, bc = (tid & 15) * 4;
  for (int k0 = 0; k0 < 1568; k0 += 32) {
    float4 av = *(const float4*)&A[(m0 + ar) * 1568 + k0 + ac];
    As[ar][ac] = av.x; As[ar][ac + 1] = av.y; As[ar][ac + 2] = av.z; As[ar][ac + 3] = av.w;
    *(float4*)&Bs[br][bc] = *(const float4*)&B[(k0 + br) * 64 + bc];
    *(float4*)&Bs[br + 16][bc] = *(const float4*)&B[(k0 + br + 16) * 64 + bc];
    __syncthreads();
    #pragma unroll
    for (int k = 0; k < 32; ++k) {
      float a0 = As[tr * 2][k], a1v = As[tr * 2 + 1][k];
      float4 bv = *(const float4*)&Bs[k][tc * 4];
      acc[0][0] += a0 * bv.x;  acc[0][1] += a0 * bv.y;  acc[0][2] += a0 * bv.z;  acc[0][3] += a0 * bv.w;
      acc[1][0] += a1v * bv.x; acc[1][1] += a1v * bv.y; acc[1][2] += a1v * bv.z; acc[1][3] += a1v * bv.w;
    }
    __syncthreads();
  }
  float4 o0 = {acc[0][0], acc[0][1], acc[0][2], acc[0][3]};
  float4 o1 = {acc[1][0], acc[1][1], acc[1][2], acc[1][3]};
  *(float4*)&C[(m0 + tr * 2) * 64 + tc * 4] = o0;
  *(float4*)&C[(m0 + tr * 2 + 1) * 64 + tc * 4] = o1;

  // fused s1/s2: each block owns full 64-wide rows m0..m0+31
  float4 va1 = *(const float4*)&a1[tc * 4];
  float4 va2 = *(const float4*)&a2[tc * 4];
  #pragma unroll
  for (int r = 0; r < 2; ++r) {
    float x1 = acc[r][0] * va1.x + acc[r][1] * va1.y + acc[r][2] * va1.z + acc[r][3] * va1.w;
    float x2 = acc[r][0] * va2.x + acc[r][1] * va2.y + acc[r][2] * va2.z + acc[r][3] * va2.w;
    #pragma unroll
    for (int w = 1; w < 16; w <<= 1) { x1 += __shfl_xor(x1, w); x2 += __shfl_xor(x2, w); }
    if (tc == 0) {
      s1[m0 + tr * 2 + r] = x1;
      s2[m0 + tr * 2 + r] = x2;
    }
  }
}

// ---------------- GAT: masked softmax + attn@Wh + ELU + heads ----------------
#define PSTR 1028
__global__ __launch_bounds__(256) void gat_kernel(
    const int* __restrict__ adj, const float* __restrict__ Wh,
    const float* __restrict__ s1, const float* __restrict__ s2,
    const float* __restrict__ actor_w, const float* __restrict__ actor_b,
    const float* __restrict__ critic_w, const float* __restrict__ critic_b,
    float* __restrict__ out)
{
  __shared__ __align__(16) float p[16 * PSTR];   // scores -> probs (unnormalized)
  __shared__ float s2s[1024];
  __shared__ float saw[64 * 16];
  __shared__ float scw[64];
  __shared__ float sab[16];
  __shared__ float denom[16];
  __shared__ float emb[16][65];
  int tid = threadIdx.x;
  int b = blockIdx.y;
  int i0 = blockIdx.x * 16;

  for (int j = tid; j < 1024; j += 256) s2s[j] = s2[b * 1024 + j];
  for (int idx2 = tid; idx2 < 64 * 16; idx2 += 256) saw[idx2] = actor_w[idx2];
  if (tid < 64) scw[tid] = critic_w[tid];
  if (tid < 16) sab[tid] = actor_b[tid];
  __syncthreads();

  // Phase A: masked leaky-relu scores + 2-pass softmax (16 lanes/row)
  {
    int il = tid >> 4, r = tid & 15;
    int i = i0 + il;
    float s1i = s1[b * 1024 + i];
    const int* arow = adj + ((long)(b * 1024 + i)) * 1024;
    float* prow = &p[il * PSTR];
    float m = -3.0e38f;
    for (int jj = 0; jj < 64; ++jj) {
      int j = r + jj * 16;
      int a = arow[j];
      float s = s1i + s2s[j];
      float e = (s > 0.f) ? s : 0.2f * s;
      e = (a > 0) ? e : NEG_BIG;
      prow[j] = e;
      m = fmaxf(m, e);
    }
    #pragma unroll
    for (int w = 1; w < 16; w <<= 1) m = fmaxf(m, __shfl_xor(m, w));
    float sum = 0.f;
    for (int jj = 0; jj < 64; ++jj) {
      int j = r + jj * 16;
      float pe = __expf(prow[j] - m);
      prow[j] = pe;
      sum += pe;
    }
    #pragma unroll
    for (int w = 1; w < 16; w <<= 1) sum += __shfl_xor(sum, w);
    if (r == 0) denom[il] = sum;
  }
  __syncthreads();

  // Phase B: h' = p @ Wh  (16x1024 @ 1024x64), 4x4 register tile per thread
  int g = tid >> 6, sub = tid & 63, ti = sub >> 4, td = sub & 15;
  float acc[4][4] = {};
  const float* WhB = Wh + ((long)b * 1024) * 64;
  int k0 = g * 256;
  for (int k = k0; k < k0 + 256; k += 4) {
    float4 a4[4];
    #pragma unroll
    for (int ii = 0; ii < 4; ++ii) a4[ii] = *(const float4*)&p[(ti * 4 + ii) * PSTR + k];
    #pragma unroll
    for (int kk = 0; kk < 4; ++kk) {
      float4 wv = *(const float4*)&WhB[(k + kk) * 64 + td * 4];
      #pragma unroll
      for (int ii = 0; ii < 4; ++ii) {
        float av = (kk == 0) ? a4[ii].x : (kk == 1) ? a4[ii].y : (kk == 2) ? a4[ii].z : a4[ii].w;
        acc[ii][0] += av * wv.x; acc[ii][1] += av * wv.y;
        acc[ii][2] += av * wv.z; acc[ii][3] += av * wv.w;
      }
    }
  }
  __syncthreads();            // all reads of p done -> safe to overlay
  float* red = p;             // [4 groups][16 rows][64 dims]
  #pragma unroll
  for (int ii = 0; ii < 4; ++ii) {
    float4 v = {acc[ii][0], acc[ii][1], acc[ii][2], acc[ii][3]};
    *(float4*)&red[(g * 16 + ti * 4 + ii) * 64 + td * 4] = v;
  }
  __syncthreads();

  // cross-group reduce + normalize + ELU
  #pragma unroll
  for (int qq = 0; qq < 4; ++qq) {
    int q = tid + qq * 256;
    int il = q >> 6, d = q & 63;
    float v = red[il * 64 + d] + red[(16 + il) * 64 + d]
            + red[(32 + il) * 64 + d] + red[(48 + il) * 64 + d];
    v /= denom[il];
    v = (v > 0.f) ? v : expm1f(v);
    emb[il][d] = v;
  }
  __syncthreads();

  // heads
  {
    int il = tid >> 4, na = tid & 15;
    float accl = sab[na];
    #pragma unroll
    for (int d = 0; d < 64; ++d) accl += emb[il][d] * saw[d * 16 + na];
    out[((long)(b * 1024 + i0 + il)) * 16 + na] = accl;
  }
  if (tid < 16) {
    float v = critic_b[0];
    #pragma unroll
    for (int d = 0; d < 64; ++d) v += emb[tid][d] * scw[d];
    out[131072 + b * 1024 + i0 + tid] = v;
  }
}

extern "C" void kernel_launch(void* const* d_in, const int* in_sizes, int n_in,
                              void* d_out, int out_size, void* d_ws, size_t ws_size,
                              hipStream_t stream)
{
  const float* obs = (const float*)d_in[0];
  const int*   adj = (const int*)d_in[1];
  const float* c1w = (const float*)d_in[2];
  const float* c1b = (const float*)d_in[3];
  const float* c2w = (const float*)d_in[4];
  const float* c2b = (const float*)d_in[5];
  const float* W   = (const float*)d_in[6];
  const float* a1  = (const float*)d_in[7];
  const float* a2  = (const float*)d_in[8];
  const float* aw  = (const float*)d_in[9];
  const float* ab  = (const float*)d_in[10];
  const float* cw  = (const float*)d_in[11];
  const float* cb  = (const float*)d_in[12];
  float* out = (float*)d_out;
  float* ws = (float*)d_ws;

  float* feats = ws;                              // 8192*1568 = 12,845,056 f32
  float* Wh    = ws + 12845056;                   // 8192*64   = 524,288 f32
  float* s1    = ws + 12845056 + 524288;          // 8192 f32
  float* s2    = s1 + 8192;                       // 8192 f32

  hipLaunchKernelGGL(cnn_kernel, dim3(1024), dim3(256), 0, stream,
                     obs, c1w, c1b, c2w, c2b, feats);
  hipLaunchKernelGGL(gemm_wh, dim3(256), dim3(256), 0, stream,
                     feats, W, a1, a2, Wh, s1, s2);
  hipLaunchKernelGGL(gat_kernel, dim3(64, 8), dim3(256), 0, stream,
                     adj, Wh, s1, s2, aw, ab, cw, cb, out);
}

// Round 3
// 120.541 us; speedup vs baseline: 1.6763x; 1.4405x over previous
//
#include <hip/hip_runtime.h>
#include <math.h>

#define NEG_BIG (-9.0e15f)

typedef __attribute__((ext_vector_type(8))) short short8;
typedef __attribute__((ext_vector_type(4))) float f32x4;

__device__ __forceinline__ short f32_to_bf16_bits(float f) {
  union { float f; unsigned u; } cv; cv.f = f;
  unsigned r = (cv.u + 0x7fffu + ((cv.u >> 16) & 1u)) >> 16;
  return (short)r;
}

// ---------------- CNN: conv1 f32 -> h1t bf16 (LDS) -> conv2 via MFMA ----------------
// 8 instances/block, 256 threads (4 waves); wave w owns instances 2w, 2w+1.
// conv2: OUT[49,32] = sum_{tap pairs} A[49,32] @ B[32,32] with
// mfma_f32_16x16x32_bf16; K = [tapA ci0..15 | tapB ci0..15].
#define IPB 8
#define H1ROWS 84            // 81 positions, rounded to 4-row swizzle groups
__global__ __launch_bounds__(256) void cnn_kernel(
    const float* __restrict__ obs, const float* __restrict__ w1,
    const float* __restrict__ b1, const float* __restrict__ w2,
    const float* __restrict__ b2, float* __restrict__ feats)
{
  __shared__ float sw1[144];
  __shared__ float sb1[16];
  __shared__ float sb2[32];
  __shared__ __align__(16) short wt[32 * 160];          // [o][k'] bf16, k' = kstep*32+which*16+ci
  __shared__ float sinp[IPB * 121];                     // zero-padded 11x11 f32
  __shared__ __align__(16) short h1t[IPB * H1ROWS * 16]; // [inst][row=pos][ci] bf16, swizzled
  int tid = threadIdx.x;
  long inst0 = (long)blockIdx.x * IPB;

  for (int i = tid; i < 144; i += 256) sw1[i] = w1[i];
  if (tid < 16) sb1[tid] = b1[tid];
  if (tid < 32) sb2[tid] = b2[tid];
  // wt[o][k']: tap = (k'>>5)*2 + ((k'>>4)&1), ci = k'&15 ; tap 9 -> zero
  for (int i = tid; i < 32 * 160; i += 256) {
    int o = i / 160, kp = i - o * 160;
    int kstep = kp >> 5, which = (kp >> 4) & 1, ci = kp & 15;
    int tap = kstep * 2 + which;
    float v = (tap < 9) ? w2[o * 144 + ci * 9 + tap] : 0.0f;
    wt[i] = f32_to_bf16_bits(v);
  }
  // zero-padded input
  for (int i = tid; i < IPB * 121; i += 256) {
    int inst = i / 121, rem = i - inst * 121;
    int py = rem / 11, px = rem - py * 11;
    float v = 0.f;
    if (py >= 1 && py <= 9 && px >= 1 && px <= 9)
      v = obs[(inst0 + inst) * 81 + (py - 1) * 9 + (px - 1)];
    sinp[inst * 121 + rem] = v;
  }
  __syncthreads();

  // ---- conv1 (f32, branch-free via padded input) -> h1t bf16, swizzled ----
  // thread t: inst = t>>5 (so wave w writes exactly insts 2w,2w+1), s = t&31
  {
    int inst = tid >> 5, s = tid & 31;
    const float* ib = &sinp[inst * 121];
    short* hw = &h1t[inst * (H1ROWS * 16)];
    for (int c = 0; c < 16; ++c) {
      float wk[9];
      #pragma unroll
      for (int k = 0; k < 9; ++k) wk[k] = sw1[c * 9 + k];
      float bias = sb1[c];
      #pragma unroll
      for (int t = 0; t < 3; ++t) {
        int px = s + t * 32;
        if (px < 81) {
          int y = (px * 456) >> 12;             // px/9 for px<81
          const float* ip = ib + px + 2 * y;    // y*11 + x in padded coords
          float a = bias
            + ip[0]  * wk[0] + ip[1]  * wk[1] + ip[2]  * wk[2]
            + ip[11] * wk[3] + ip[12] * wk[4] + ip[13] * wk[5]
            + ip[22] * wk[6] + ip[23] * wk[7] + ip[24] * wk[8];
          a = fmaxf(a, 0.f);
          int idx = (px * 16 + c) ^ (((px >> 2) & 3) << 3);  // XOR bank swizzle
          hw[idx] = f32_to_bf16_bits(a);
        }
      }
    }
  }
  // NO barrier: each wave reads only the h1t rows it just wrote.

  // ---- conv2 via MFMA ----
  int lane = tid & 63;
  int wv = tid >> 6;
  int g = lane >> 4;            // k-subgroup
  int which = g >> 1;           // tap-in-pair
  int half = g & 1;             // channel half (ci 0-7 / 8-15)
  int colr = lane & 15;         // A-row / D-col index within tile

  // per-lane tap offsets for the 5 K-steps
  const int offtab[9] = {0, 1, 2, 9, 10, 11, 18, 19, 20};
  int myoff[5];
  #pragma unroll
  for (int k = 0; k < 5; ++k) {
    int tap = k * 2 + which;
    myoff[k] = (tap < 9) ? offtab[tap] : 0;
  }
  // A-row positions per M-tile (invalid rows -> pos 0, results discarded)
  int posm[4];
  #pragma unroll
  for (int mt = 0; mt < 4; ++mt) {
    int p = mt * 16 + colr;
    posm[mt] = (p < 49) ? (p / 7) * 9 + (p % 7) : 0;
  }
  // B fragments: lane holds B[g*8+j][colr] = wt[o][kstep*32 + g*8 + j]
  short8 bf[2][5];
  #pragma unroll
  for (int nt = 0; nt < 2; ++nt)
    #pragma unroll
    for (int k = 0; k < 5; ++k)
      bf[nt][k] = *(const short8*)&wt[(nt * 16 + colr) * 160 + k * 32 + g * 8];

  #pragma unroll
  for (int ii = 0; ii < 2; ++ii) {
    int inst = wv * 2 + ii;
    const short* hb = &h1t[inst * (H1ROWS * 16)];
    float* fb = feats + (inst0 + inst) * 1568;
    #pragma unroll
    for (int mt = 0; mt < 4; ++mt) {
      short8 af[5];
      #pragma unroll
      for (int k = 0; k < 5; ++k) {
        int row = posm[mt] + myoff[k];
        int idx = (row * 16 + half * 8) ^ (((row >> 2) & 3) << 3);
        af[k] = *(const short8*)&hb[idx];
      }
      #pragma unroll
      for (int nt = 0; nt < 2; ++nt) {
        f32x4 acc = {0.f, 0.f, 0.f, 0.f};
        #pragma unroll
        for (int k = 0; k < 5; ++k)
          acc = __builtin_amdgcn_mfma_f32_16x16x32_bf16(af[k], bf[nt][k], acc, 0, 0, 0);
        // D: lane holds D[g*4+r][colr]; feats stored transposed: [inst][p*32+o]
        int o = nt * 16 + colr;
        float bias = sb2[o];
        #pragma unroll
        for (int r = 0; r < 4; ++r) {
          int p = mt * 16 + g * 4 + r;
          if (p < 49) fb[p * 32 + o] = fmaxf(acc[r] + bias, 0.f);
        }
      }
    }
  }
}

// ------- GEMM: Wh = feats_t(8192x1568) @ Wperm(1568x64), fused s1/s2 -------
// feats K-dim is permuted (k' = p*32+o); compensate by permuting W rows.
__global__ __launch_bounds__(256) void gemm_wh(
    const float* __restrict__ A, const float* __restrict__ B,
    const float* __restrict__ a1, const float* __restrict__ a2,
    float* __restrict__ C, float* __restrict__ s1, float* __restrict__ s2)
{
  __shared__ float As[32][33];
  __shared__ __align__(16) float Bs[32][64];
  int tid = threadIdx.x;
  long m0 = (long)blockIdx.x * 32;
  int tr = tid >> 4, tc = tid & 15;
  float acc[2][4] = {{0, 0, 0, 0}, {0, 0, 0, 0}};
  int ar = tid >> 3, ac = (tid & 7) * 4;
  int br = tid >> 4, bc = (tid & 15) * 4;
  for (int k0 = 0; k0 < 1568; k0 += 32) {
    float4 av = *(const float4*)&A[(m0 + ar) * 1568 + k0 + ac];
    As[ar][ac] = av.x; As[ar][ac + 1] = av.y; As[ar][ac + 2] = av.z; As[ar][ac + 3] = av.w;
    int kk1 = k0 + br, kk2 = k0 + br + 16;
    *(float4*)&Bs[br][bc]      = *(const float4*)&B[((kk1 & 31) * 49 + (kk1 >> 5)) * 64 + bc];
    *(float4*)&Bs[br + 16][bc] = *(const float4*)&B[((kk2 & 31) * 49 + (kk2 >> 5)) * 64 + bc];
    __syncthreads();
    #pragma unroll
    for (int k = 0; k < 32; ++k) {
      float a0 = As[tr * 2][k], a1v = As[tr * 2 + 1][k];
      float4 bv = *(const float4*)&Bs[k][tc * 4];
      acc[0][0] += a0 * bv.x;  acc[0][1] += a0 * bv.y;  acc[0][2] += a0 * bv.z;  acc[0][3] += a0 * bv.w;
      acc[1][0] += a1v * bv.x; acc[1][1] += a1v * bv.y; acc[1][2] += a1v * bv.z; acc[1][3] += a1v * bv.w;
    }
    __syncthreads();
  }
  float4 o0 = {acc[0][0], acc[0][1], acc[0][2], acc[0][3]};
  float4 o1 = {acc[1][0], acc[1][1], acc[1][2], acc[1][3]};
  *(float4*)&C[(m0 + tr * 2) * 64 + tc * 4] = o0;
  *(float4*)&C[(m0 + tr * 2 + 1) * 64 + tc * 4] = o1;

  float4 va1 = *(const float4*)&a1[tc * 4];
  float4 va2 = *(const float4*)&a2[tc * 4];
  #pragma unroll
  for (int r = 0; r < 2; ++r) {
    float x1 = acc[r][0] * va1.x + acc[r][1] * va1.y + acc[r][2] * va1.z + acc[r][3] * va1.w;
    float x2 = acc[r][0] * va2.x + acc[r][1] * va2.y + acc[r][2] * va2.z + acc[r][3] * va2.w;
    #pragma unroll
    for (int w = 1; w < 16; w <<= 1) { x1 += __shfl_xor(x1, w); x2 += __shfl_xor(x2, w); }
    if (tc == 0) {
      s1[m0 + tr * 2 + r] = x1;
      s2[m0 + tr * 2 + r] = x2;
    }
  }
}

// ---------------- GAT: masked softmax + attn@Wh + ELU + heads ----------------
#define PSTR 1028
__global__ __launch_bounds__(256) void gat_kernel(
    const int* __restrict__ adj, const float* __restrict__ Wh,
    const float* __restrict__ s1, const float* __restrict__ s2,
    const float* __restrict__ actor_w, const float* __restrict__ actor_b,
    const float* __restrict__ critic_w, const float* __restrict__ critic_b,
    float* __restrict__ out)
{
  __shared__ __align__(16) float p[16 * PSTR];
  __shared__ float s2s[1024];
  __shared__ float saw[64 * 16];
  __shared__ float scw[64];
  __shared__ float sab[16];
  __shared__ float denom[16];
  __shared__ float emb[16][65];
  int tid = threadIdx.x;
  int b = blockIdx.y;
  int i0 = blockIdx.x * 16;

  for (int j = tid; j < 1024; j += 256) s2s[j] = s2[b * 1024 + j];
  for (int idx2 = tid; idx2 < 64 * 16; idx2 += 256) saw[idx2] = actor_w[idx2];
  if (tid < 64) scw[tid] = critic_w[tid];
  if (tid < 16) sab[tid] = actor_b[tid];
  __syncthreads();

  {
    int il = tid >> 4, r = tid & 15;
    int i = i0 + il;
    float s1i = s1[b * 1024 + i];
    const int* arow = adj + ((long)(b * 1024 + i)) * 1024;
    float* prow = &p[il * PSTR];
    float m = -3.0e38f;
    for (int jj = 0; jj < 64; ++jj) {
      int j = r + jj * 16;
      int a = arow[j];
      float s = s1i + s2s[j];
      float e = (s > 0.f) ? s : 0.2f * s;
      e = (a > 0) ? e : NEG_BIG;
      prow[j] = e;
      m = fmaxf(m, e);
    }
    #pragma unroll
    for (int w = 1; w < 16; w <<= 1) m = fmaxf(m, __shfl_xor(m, w));
    float sum = 0.f;
    for (int jj = 0; jj < 64; ++jj) {
      int j = r + jj * 16;
      float pe = __expf(prow[j] - m);
      prow[j] = pe;
      sum += pe;
    }
    #pragma unroll
    for (int w = 1; w < 16; w <<= 1) sum += __shfl_xor(sum, w);
    if (r == 0) denom[il] = sum;
  }
  __syncthreads();

  int g = tid >> 6, sub = tid & 63, ti = sub >> 4, td = sub & 15;
  float acc[4][4] = {};
  const float* WhB = Wh + ((long)b * 1024) * 64;
  int k0 = g * 256;
  for (int k = k0; k < k0 + 256; k += 4) {
    float4 a4[4];
    #pragma unroll
    for (int ii = 0; ii < 4; ++ii) a4[ii] = *(const float4*)&p[(ti * 4 + ii) * PSTR + k];
    #pragma unroll
    for (int kk = 0; kk < 4; ++kk) {
      float4 wv2 = *(const float4*)&WhB[(k + kk) * 64 + td * 4];
      #pragma unroll
      for (int ii = 0; ii < 4; ++ii) {
        float av = (kk == 0) ? a4[ii].x : (kk == 1) ? a4[ii].y : (kk == 2) ? a4[ii].z : a4[ii].w;
        acc[ii][0] += av * wv2.x; acc[ii][1] += av * wv2.y;
        acc[ii][2] += av * wv2.z; acc[ii][3] += av * wv2.w;
      }
    }
  }
  __syncthreads();
  float* red = p;
  #pragma unroll
  for (int ii = 0; ii < 4; ++ii) {
    float4 v = {acc[ii][0], acc[ii][1], acc[ii][2], acc[ii][3]};
    *(float4*)&red[(g * 16 + ti * 4 + ii) * 64 + td * 4] = v;
  }
  __syncthreads();

  #pragma unroll
  for (int qq = 0; qq < 4; ++qq) {
    int q = tid + qq * 256;
    int il = q >> 6, d = q & 63;
    float v = red[il * 64 + d] + red[(16 + il) * 64 + d]
            + red[(32 + il) * 64 + d] + red[(48 + il) * 64 + d];
    v /= denom[il];
    v = (v > 0.f) ? v : expm1f(v);
    emb[il][d] = v;
  }
  __syncthreads();

  {
    int il = tid >> 4, na = tid & 15;
    float accl = sab[na];
    #pragma unroll
    for (int d = 0; d < 64; ++d) accl += emb[il][d] * saw[d * 16 + na];
    out[((long)(b * 1024 + i0 + il)) * 16 + na] = accl;
  }
  if (tid < 16) {
    float v = critic_b[0];
    #pragma unroll
    for (int d = 0; d < 64; ++d) v += emb[tid][d] * scw[d];
    out[131072 + b * 1024 + i0 + tid] = v;
  }
}

extern "C" void kernel_launch(void* const* d_in, const int* in_sizes, int n_in,
                              void* d_out, int out_size, void* d_ws, size_t ws_size,
                              hipStream_t stream)
{
  const float* obs = (const float*)d_in[0];
  const int*   adj = (const int*)d_in[1];
  const float* c1w = (const float*)d_in[2];
  const float* c1b = (const float*)d_in[3];
  const float* c2w = (const float*)d_in[4];
  const float* c2b = (const float*)d_in[5];
  const float* W   = (const float*)d_in[6];
  const float* a1  = (const float*)d_in[7];
  const float* a2  = (const float*)d_in[8];
  const float* aw  = (const float*)d_in[9];
  const float* ab  = (const float*)d_in[10];
  const float* cw  = (const float*)d_in[11];
  const float* cb  = (const float*)d_in[12];
  float* out = (float*)d_out;
  float* ws = (float*)d_ws;

  float* feats = ws;                              // transposed per-inst: [p*32+o]
  float* Wh    = ws + 12845056;
  float* s1    = ws + 12845056 + 524288;
  float* s2    = s1 + 8192;

  hipLaunchKernelGGL(cnn_kernel, dim3(1024), dim3(256), 0, stream,
                     obs, c1w, c1b, c2w, c2b, feats);
  hipLaunchKernelGGL(gemm_wh, dim3(256), dim3(256), 0, stream,
                     feats, W, a1, a2, Wh, s1, s2);
  hipLaunchKernelGGL(gat_kernel, dim3(64, 8), dim3(256), 0, stream,
                     adj, Wh, s1, s2, aw, ab, cw, cb, out);
}

// Round 4
// 80.194 us; speedup vs baseline: 2.5197x; 1.5031x over previous
//
#include <hip/hip_runtime.h>
#include <math.h>

#define NEG_BIG (-9.0e15f)

typedef __attribute__((ext_vector_type(8))) short short8;
typedef __attribute__((ext_vector_type(4))) float f32x4;

__device__ __forceinline__ short f32_to_bf16_bits(float f) {
  union { float f; unsigned u; } cv; cv.f = f;
  unsigned r = (cv.u + 0x7fffu + ((cv.u >> 16) & 1u)) >> 16;
  return (short)r;
}

// ---- prep: Wt_bf16[64][1568] = transpose(W[1568][64]) ----
__global__ __launch_bounds__(256) void wt_prep(const float* __restrict__ W,
                                               short* __restrict__ Wt) {
  int idx = blockIdx.x * 256 + threadIdx.x;
  if (idx < 1568 * 64) {
    int k = idx >> 6, n = idx & 63;
    Wt[n * 1568 + k] = f32_to_bf16_bits(W[idx]);
  }
}

// ---------------- fused CNN + Wh GEMM + s1/s2 ----------------
// 8 instances/block, 4 waves; wave w owns instances 2w,2w+1 through conv1/conv2.
// conv2 (MFMA) writes bf16 feats into LDS (overlaying h1t); then each wave
// computes a 16-col slice of Wh[8,64] = sfeat @ W^T with 49 chained MFMAs.
#define IPB 8
#define FSTR 1608            // sfeat row stride in shorts (804 dwords = 4 mod 32)
__global__ __launch_bounds__(256) void cnn_gemm_kernel(
    const float* __restrict__ obs, const float* __restrict__ w1,
    const float* __restrict__ b1, const float* __restrict__ w2,
    const float* __restrict__ b2, const short* __restrict__ Wt,
    const float* __restrict__ a1, const float* __restrict__ a2,
    float* __restrict__ Wh, float* __restrict__ s1, float* __restrict__ s2)
{
  __shared__ float sw1[144];
  __shared__ float sb1[16];
  __shared__ float sb2[32];
  __shared__ __align__(16) short wt[32 * 160];      // conv2 weights [o][k']
  __shared__ float sinp[IPB * 121];                 // padded 11x11; later sp1/sp2
  __shared__ __align__(16) short ubuf[IPB * FSTR];  // h1t (swizzled) -> sfeat bf16
  int tid = threadIdx.x;
  long inst0 = (long)blockIdx.x * IPB;

  for (int i = tid; i < 144; i += 256) sw1[i] = w1[i];
  if (tid < 16) sb1[tid] = b1[tid];
  if (tid < 32) sb2[tid] = b2[tid];
  for (int i = tid; i < 32 * 160; i += 256) {
    int o = i / 160, kp = i - o * 160;
    int kstep = kp >> 5, which = (kp >> 4) & 1, ci = kp & 15;
    int tap = kstep * 2 + which;
    float v = (tap < 9) ? w2[o * 144 + ci * 9 + tap] : 0.0f;
    wt[i] = f32_to_bf16_bits(v);
  }
  for (int i = tid; i < IPB * 121; i += 256) {
    int inst = i / 121, rem = i - inst * 121;
    int py = rem / 11, px = rem - py * 11;
    float v = 0.f;
    if (py >= 1 && py <= 9 && px >= 1 && px <= 9)
      v = obs[(inst0 + inst) * 81 + (py - 1) * 9 + (px - 1)];
    sinp[inst * 121 + rem] = v;
  }
  __syncthreads();

  // ---- conv1 (f32) -> h1t bf16 swizzled, per-wave-owned regions ----
  {
    int inst = tid >> 5, s = tid & 31;
    const float* ib = &sinp[inst * 121];
    short* hw = &ubuf[inst * FSTR];
    for (int c = 0; c < 16; ++c) {
      float wk[9];
      #pragma unroll
      for (int k = 0; k < 9; ++k) wk[k] = sw1[c * 9 + k];
      float bias = sb1[c];
      #pragma unroll
      for (int t = 0; t < 3; ++t) {
        int px = s + t * 32;
        if (px < 81) {
          int y = (px * 456) >> 12;
          const float* ip = ib + px + 2 * y;
          float a = bias
            + ip[0]  * wk[0] + ip[1]  * wk[1] + ip[2]  * wk[2]
            + ip[11] * wk[3] + ip[12] * wk[4] + ip[13] * wk[5]
            + ip[22] * wk[6] + ip[23] * wk[7] + ip[24] * wk[8];
          a = fmaxf(a, 0.f);
          int idx = (px * 16 + c) ^ (((px >> 2) & 3) << 3);
          hw[idx] = f32_to_bf16_bits(a);
        }
      }
    }
  }
  // no barrier: each wave consumes only the h1t rows it wrote.

  // ---- conv2 via MFMA; results -> sfeat bf16 (same per-inst region) ----
  int lane = tid & 63;
  int wv = tid >> 6;
  int g = lane >> 4;
  int which = g >> 1;
  int half = g & 1;
  int colr = lane & 15;

  const int offtab[9] = {0, 1, 2, 9, 10, 11, 18, 19, 20};
  int myoff[5];
  #pragma unroll
  for (int k = 0; k < 5; ++k) {
    int tap = k * 2 + which;
    myoff[k] = (tap < 9) ? offtab[tap] : 0;
  }
  int posm[4];
  #pragma unroll
  for (int mt = 0; mt < 4; ++mt) {
    int p = mt * 16 + colr;
    posm[mt] = (p < 49) ? (p / 7) * 9 + (p % 7) : 0;
  }
  short8 bfw[2][5];
  #pragma unroll
  for (int nt = 0; nt < 2; ++nt)
    #pragma unroll
    for (int k = 0; k < 5; ++k)
      bfw[nt][k] = *(const short8*)&wt[(nt * 16 + colr) * 160 + k * 32 + g * 8];

  #pragma unroll
  for (int ii = 0; ii < 2; ++ii) {
    int inst = wv * 2 + ii;
    const short* hb = &ubuf[inst * FSTR];
    short* fb = &ubuf[inst * FSTR];
    f32x4 acc[4][2];
    #pragma unroll
    for (int mt = 0; mt < 4; ++mt) {
      short8 af[5];
      #pragma unroll
      for (int k = 0; k < 5; ++k) {
        int row = posm[mt] + myoff[k];
        int idx = (row * 16 + half * 8) ^ (((row >> 2) & 3) << 3);
        af[k] = *(const short8*)&hb[idx];
      }
      #pragma unroll
      for (int nt = 0; nt < 2; ++nt) {
        f32x4 a0 = {0.f, 0.f, 0.f, 0.f};
        #pragma unroll
        for (int k = 0; k < 5; ++k)
          a0 = __builtin_amdgcn_mfma_f32_16x16x32_bf16(af[k], bfw[nt][k], a0, 0, 0, 0);
        acc[mt][nt] = a0;
      }
    }
    // all h1t reads for this inst are complete (data dep) -> overlay with sfeat
    #pragma unroll
    for (int mt = 0; mt < 4; ++mt) {
      #pragma unroll
      for (int nt = 0; nt < 2; ++nt) {
        int o = nt * 16 + colr;
        float bias = sb2[o];
        #pragma unroll
        for (int r = 0; r < 4; ++r) {
          int p = mt * 16 + g * 4 + r;
          if (p < 49)
            fb[o * 49 + p] = f32_to_bf16_bits(fmaxf(acc[mt][nt][r] + bias, 0.f));
        }
      }
    }
  }
  __syncthreads();   // all instances' sfeat ready; sinp free for reuse

  // ---- Wh GEMM: wave wv computes columns [16wv, 16wv+16) for all 8 insts ----
  {
    int arow = colr & 7;
    const short* Wrow = Wt + (wv * 16 + colr) * 1568;
    f32x4 acc2 = {0.f, 0.f, 0.f, 0.f};
    for (int ks = 0; ks < 49; ++ks) {
      short8 af = *(const short8*)&ubuf[arow * FSTR + ks * 32 + g * 8];
      short8 bf = *(const short8*)&Wrow[ks * 32 + g * 8];
      acc2 = __builtin_amdgcn_mfma_f32_16x16x32_bf16(af, bf, acc2, 0, 0, 0);
    }
    float a1c = a1[wv * 16 + colr];
    float a2c = a2[wv * 16 + colr];
    float* sp1 = sinp;          // [4][8]
    float* sp2 = sinp + 32;     // [4][8]
    if (g < 2) {
      #pragma unroll
      for (int r = 0; r < 4; ++r) {
        int inst = g * 4 + r;
        float v = acc2[r];
        Wh[(inst0 + inst) * 64 + wv * 16 + colr] = v;
        float x1 = v * a1c, x2 = v * a2c;
        #pragma unroll
        for (int w = 1; w < 16; w <<= 1) { x1 += __shfl_xor(x1, w); x2 += __shfl_xor(x2, w); }
        if (colr == 0) { sp1[wv * 8 + inst] = x1; sp2[wv * 8 + inst] = x2; }
      }
    }
  }
  __syncthreads();
  if (tid < 8) {
    float* sp1 = sinp;
    float* sp2 = sinp + 32;
    s1[inst0 + tid] = sp1[tid] + sp1[8 + tid] + sp1[16 + tid] + sp1[24 + tid];
    s2[inst0 + tid] = sp2[tid] + sp2[8 + tid] + sp2[16 + tid] + sp2[24 + tid];
  }
}

// ---------------- GAT: masked softmax + attn@Wh + ELU + heads ----------------
#define PSTR 1028
__global__ __launch_bounds__(256) void gat_kernel(
    const int* __restrict__ adj, const float* __restrict__ Wh,
    const float* __restrict__ s1, const float* __restrict__ s2,
    const float* __restrict__ actor_w, const float* __restrict__ actor_b,
    const float* __restrict__ critic_w, const float* __restrict__ critic_b,
    float* __restrict__ out)
{
  __shared__ __align__(16) float p[16 * PSTR];
  __shared__ float s2s[1024];
  __shared__ float saw[64 * 16];
  __shared__ float scw[64];
  __shared__ float sab[16];
  __shared__ float denom[16];
  __shared__ float emb[16][65];
  int tid = threadIdx.x;
  int b = blockIdx.y;
  int i0 = blockIdx.x * 16;

  for (int j = tid; j < 1024; j += 256) s2s[j] = s2[b * 1024 + j];
  for (int idx2 = tid; idx2 < 64 * 16; idx2 += 256) saw[idx2] = actor_w[idx2];
  if (tid < 64) scw[tid] = critic_w[tid];
  if (tid < 16) sab[tid] = actor_b[tid];
  __syncthreads();

  {
    int il = tid >> 4, r = tid & 15;
    int i = i0 + il;
    float s1i = s1[b * 1024 + i];
    const int* arow = adj + ((long)(b * 1024 + i)) * 1024;
    float* prow = &p[il * PSTR];
    float m = -3.0e38f;
    for (int jj = 0; jj < 64; ++jj) {
      int j = r + jj * 16;
      int a = arow[j];
      float s = s1i + s2s[j];
      float e = (s > 0.f) ? s : 0.2f * s;
      e = (a > 0) ? e : NEG_BIG;
      prow[j] = e;
      m = fmaxf(m, e);
    }
    #pragma unroll
    for (int w = 1; w < 16; w <<= 1) m = fmaxf(m, __shfl_xor(m, w));
    float sum = 0.f;
    for (int jj = 0; jj < 64; ++jj) {
      int j = r + jj * 16;
      float pe = __expf(prow[j] - m);
      prow[j] = pe;
      sum += pe;
    }
    #pragma unroll
    for (int w = 1; w < 16; w <<= 1) sum += __shfl_xor(sum, w);
    if (r == 0) denom[il] = sum;
  }
  __syncthreads();

  int g = tid >> 6, sub = tid & 63, ti = sub >> 4, td = sub & 15;
  float acc[4][4] = {};
  const float* WhB = Wh + ((long)b * 1024) * 64;
  int k0 = g * 256;
  for (int k = k0; k < k0 + 256; k += 4) {
    float4 a4[4];
    #pragma unroll
    for (int ii = 0; ii < 4; ++ii) a4[ii] = *(const float4*)&p[(ti * 4 + ii) * PSTR + k];
    #pragma unroll
    for (int kk = 0; kk < 4; ++kk) {
      float4 wv2 = *(const float4*)&WhB[(k + kk) * 64 + td * 4];
      #pragma unroll
      for (int ii = 0; ii < 4; ++ii) {
        float av = (kk == 0) ? a4[ii].x : (kk == 1) ? a4[ii].y : (kk == 2) ? a4[ii].z : a4[ii].w;
        acc[ii][0] += av * wv2.x; acc[ii][1] += av * wv2.y;
        acc[ii][2] += av * wv2.z; acc[ii][3] += av * wv2.w;
      }
    }
  }
  __syncthreads();
  float* red = p;
  #pragma unroll
  for (int ii = 0; ii < 4; ++ii) {
    float4 v = {acc[ii][0], acc[ii][1], acc[ii][2], acc[ii][3]};
    *(float4*)&red[(g * 16 + ti * 4 + ii) * 64 + td * 4] = v;
  }
  __syncthreads();

  #pragma unroll
  for (int qq = 0; qq < 4; ++qq) {
    int q = tid + qq * 256;
    int il = q >> 6, d = q & 63;
    float v = red[il * 64 + d] + red[(16 + il) * 64 + d]
            + red[(32 + il) * 64 + d] + red[(48 + il) * 64 + d];
    v /= denom[il];
    v = (v > 0.f) ? v : expm1f(v);
    emb[il][d] = v;
  }
  __syncthreads();

  {
    int il = tid >> 4, na = tid & 15;
    float accl = sab[na];
    #pragma unroll
    for (int d = 0; d < 64; ++d) accl += emb[il][d] * saw[d * 16 + na];
    out[((long)(b * 1024 + i0 + il)) * 16 + na] = accl;
  }
  if (tid < 16) {
    float v = critic_b[0];
    #pragma unroll
    for (int d = 0; d < 64; ++d) v += emb[tid][d] * scw[d];
    out[131072 + b * 1024 + i0 + tid] = v;
  }
}

extern "C" void kernel_launch(void* const* d_in, const int* in_sizes, int n_in,
                              void* d_out, int out_size, void* d_ws, size_t ws_size,
                              hipStream_t stream)
{
  const float* obs = (const float*)d_in[0];
  const int*   adj = (const int*)d_in[1];
  const float* c1w = (const float*)d_in[2];
  const float* c1b = (const float*)d_in[3];
  const float* c2w = (const float*)d_in[4];
  const float* c2b = (const float*)d_in[5];
  const float* W   = (const float*)d_in[6];
  const float* a1  = (const float*)d_in[7];
  const float* a2  = (const float*)d_in[8];
  const float* aw  = (const float*)d_in[9];
  const float* ab  = (const float*)d_in[10];
  const float* cw  = (const float*)d_in[11];
  const float* cb  = (const float*)d_in[12];
  float* out = (float*)d_out;
  float* ws = (float*)d_ws;

  float* Wh  = ws;                        // 8192*64 = 524288 f32
  float* s1  = ws + 524288;               // 8192
  float* s2  = s1 + 8192;                 // 8192
  short* Wt  = (short*)(s2 + 8192);       // 64*1568 bf16

  hipLaunchKernelGGL(wt_prep, dim3((1568 * 64 + 255) / 256), dim3(256), 0, stream, W, Wt);
  hipLaunchKernelGGL(cnn_gemm_kernel, dim3(1024), dim3(256), 0, stream,
                     obs, c1w, c1b, c2w, c2b, Wt, a1, a2, Wh, s1, s2);
  hipLaunchKernelGGL(gat_kernel, dim3(64, 8), dim3(256), 0, stream,
                     adj, Wh, s1, s2, aw, ab, cw, cb, out);
}

// Round 5
// 67.695 us; speedup vs baseline: 2.9850x; 1.1846x over previous
//
#include <hip/hip_runtime.h>
#include <math.h>

#define NEG_BIG (-9.0e15f)

typedef __attribute__((ext_vector_type(8))) short short8;
typedef __attribute__((ext_vector_type(4))) short short4v;
typedef __attribute__((ext_vector_type(4))) float f32x4;

__device__ __forceinline__ short f32_to_bf16_bits(float f) {
  union { float f; unsigned u; } cv; cv.f = f;
  unsigned r = (cv.u + 0x7fffu + ((cv.u >> 16) & 1u)) >> 16;
  return (short)r;
}

// ---- prep: Wt_bf16[64][1568] = transpose(W[1568][64]) ----
__global__ __launch_bounds__(256) void wt_prep(const float* __restrict__ W,
                                               short* __restrict__ Wt) {
  int idx = blockIdx.x * 256 + threadIdx.x;
  if (idx < 1568 * 64) {
    int k = idx >> 6, n = idx & 63;
    Wt[n * 1568 + k] = f32_to_bf16_bits(W[idx]);
  }
}

// ---------------- fused CNN + Wh GEMM + s1/s2 ----------------
#define IPB 8
#define FSTR 1608
__global__ __launch_bounds__(256) void cnn_gemm_kernel(
    const float* __restrict__ obs, const float* __restrict__ w1,
    const float* __restrict__ b1, const float* __restrict__ w2,
    const float* __restrict__ b2, const short* __restrict__ Wt,
    const float* __restrict__ a1, const float* __restrict__ a2,
    short* __restrict__ Whb, float* __restrict__ s1, float* __restrict__ s2)
{
  __shared__ float sw1[144];
  __shared__ float sb1[16];
  __shared__ float sb2[32];
  __shared__ __align__(16) short wt[32 * 160];
  __shared__ float sinp[IPB * 121];
  __shared__ __align__(16) short ubuf[IPB * FSTR];
  int tid = threadIdx.x;
  long inst0 = (long)blockIdx.x * IPB;

  for (int i = tid; i < 144; i += 256) sw1[i] = w1[i];
  if (tid < 16) sb1[tid] = b1[tid];
  if (tid < 32) sb2[tid] = b2[tid];
  for (int i = tid; i < 32 * 160; i += 256) {
    int o = i / 160, kp = i - o * 160;
    int kstep = kp >> 5, which = (kp >> 4) & 1, ci = kp & 15;
    int tap = kstep * 2 + which;
    float v = (tap < 9) ? w2[o * 144 + ci * 9 + tap] : 0.0f;
    wt[i] = f32_to_bf16_bits(v);
  }
  for (int i = tid; i < IPB * 121; i += 256) {
    int inst = i / 121, rem = i - inst * 121;
    int py = rem / 11, px = rem - py * 11;
    float v = 0.f;
    if (py >= 1 && py <= 9 && px >= 1 && px <= 9)
      v = obs[(inst0 + inst) * 81 + (py - 1) * 9 + (px - 1)];
    sinp[inst * 121 + rem] = v;
  }
  __syncthreads();

  // ---- conv1 (f32) -> h1t bf16 swizzled, per-wave-owned regions ----
  {
    int inst = tid >> 5, s = tid & 31;
    const float* ib = &sinp[inst * 121];
    short* hw = &ubuf[inst * FSTR];
    for (int c = 0; c < 16; ++c) {
      float wk[9];
      #pragma unroll
      for (int k = 0; k < 9; ++k) wk[k] = sw1[c * 9 + k];
      float bias = sb1[c];
      #pragma unroll
      for (int t = 0; t < 3; ++t) {
        int px = s + t * 32;
        if (px < 81) {
          int y = (px * 456) >> 12;
          const float* ip = ib + px + 2 * y;
          float a = bias
            + ip[0]  * wk[0] + ip[1]  * wk[1] + ip[2]  * wk[2]
            + ip[11] * wk[3] + ip[12] * wk[4] + ip[13] * wk[5]
            + ip[22] * wk[6] + ip[23] * wk[7] + ip[24] * wk[8];
          a = fmaxf(a, 0.f);
          int idx = (px * 16 + c) ^ (((px >> 2) & 3) << 3);
          hw[idx] = f32_to_bf16_bits(a);
        }
      }
    }
  }

  // ---- conv2 via MFMA; results -> sfeat bf16 (same per-inst region) ----
  int lane = tid & 63;
  int wv = tid >> 6;
  int g = lane >> 4;
  int which = g >> 1;
  int half = g & 1;
  int colr = lane & 15;

  const int offtab[9] = {0, 1, 2, 9, 10, 11, 18, 19, 20};
  int myoff[5];
  #pragma unroll
  for (int k = 0; k < 5; ++k) {
    int tap = k * 2 + which;
    myoff[k] = (tap < 9) ? offtab[tap] : 0;
  }
  int posm[4];
  #pragma unroll
  for (int mt = 0; mt < 4; ++mt) {
    int p = mt * 16 + colr;
    posm[mt] = (p < 49) ? (p / 7) * 9 + (p % 7) : 0;
  }
  short8 bfw[2][5];
  #pragma unroll
  for (int nt = 0; nt < 2; ++nt)
    #pragma unroll
    for (int k = 0; k < 5; ++k)
      bfw[nt][k] = *(const short8*)&wt[(nt * 16 + colr) * 160 + k * 32 + g * 8];

  #pragma unroll
  for (int ii = 0; ii < 2; ++ii) {
    int inst = wv * 2 + ii;
    const short* hb = &ubuf[inst * FSTR];
    short* fb = &ubuf[inst * FSTR];
    f32x4 acc[4][2];
    #pragma unroll
    for (int mt = 0; mt < 4; ++mt) {
      short8 af[5];
      #pragma unroll
      for (int k = 0; k < 5; ++k) {
        int row = posm[mt] + myoff[k];
        int idx = (row * 16 + half * 8) ^ (((row >> 2) & 3) << 3);
        af[k] = *(const short8*)&hb[idx];
      }
      #pragma unroll
      for (int nt = 0; nt < 2; ++nt) {
        f32x4 a0 = {0.f, 0.f, 0.f, 0.f};
        #pragma unroll
        for (int k = 0; k < 5; ++k)
          a0 = __builtin_amdgcn_mfma_f32_16x16x32_bf16(af[k], bfw[nt][k], a0, 0, 0, 0);
        acc[mt][nt] = a0;
      }
    }
    #pragma unroll
    for (int mt = 0; mt < 4; ++mt) {
      #pragma unroll
      for (int nt = 0; nt < 2; ++nt) {
        int o = nt * 16 + colr;
        float bias = sb2[o];
        #pragma unroll
        for (int r = 0; r < 4; ++r) {
          int p = mt * 16 + g * 4 + r;
          if (p < 49)
            fb[o * 49 + p] = f32_to_bf16_bits(fmaxf(acc[mt][nt][r] + bias, 0.f));
        }
      }
    }
  }
  __syncthreads();

  // ---- Wh GEMM: wave wv computes cols [16wv,16wv+16); Whb stored bf16 T ----
  {
    int arow = colr & 7;
    const short* Wrow = Wt + (wv * 16 + colr) * 1568;
    f32x4 acc2 = {0.f, 0.f, 0.f, 0.f};
    for (int ks = 0; ks < 49; ++ks) {
      short8 af = *(const short8*)&ubuf[arow * FSTR + ks * 32 + g * 8];
      short8 bf = *(const short8*)&Wrow[ks * 32 + g * 8];
      acc2 = __builtin_amdgcn_mfma_f32_16x16x32_bf16(af, bf, acc2, 0, 0, 0);
    }
    float a1c = a1[wv * 16 + colr];
    float a2c = a2[wv * 16 + colr];
    float* sp1 = sinp;
    float* sp2 = sinp + 32;
    if (g < 2) {
      long bidx = inst0 >> 10;
      int node0 = (int)(inst0 & 1023) + g * 4;
      short4v pk;
      #pragma unroll
      for (int r = 0; r < 4; ++r) pk[r] = f32_to_bf16_bits(acc2[r]);
      *(short4v*)&Whb[(bidx * 64 + wv * 16 + colr) * 1024 + node0] = pk;
      #pragma unroll
      for (int r = 0; r < 4; ++r) {
        int inst = g * 4 + r;
        float v = acc2[r];
        float x1 = v * a1c, x2 = v * a2c;
        #pragma unroll
        for (int w = 1; w < 16; w <<= 1) { x1 += __shfl_xor(x1, w); x2 += __shfl_xor(x2, w); }
        if (colr == 0) { sp1[wv * 8 + inst] = x1; sp2[wv * 8 + inst] = x2; }
      }
    }
  }
  __syncthreads();
  if (tid < 8) {
    float* sp1 = sinp;
    float* sp2 = sinp + 32;
    s1[inst0 + tid] = sp1[tid] + sp1[8 + tid] + sp1[16 + tid] + sp1[24 + tid];
    s2[inst0 + tid] = sp2[tid] + sp2[8 + tid] + sp2[16 + tid] + sp2[24 + tid];
  }
}

// ---------------- GAT: mask-reg softmax + MFMA PV + ELU + heads ----------------
#define PSTR2 1096   // bf16 row stride (16B-aligned rows)
__global__ __launch_bounds__(256) void gat_kernel(
    const int* __restrict__ adj, const short* __restrict__ Whb,
    const float* __restrict__ s1, const float* __restrict__ s2,
    const float* __restrict__ actor_w, const float* __restrict__ actor_b,
    const float* __restrict__ critic_w, const float* __restrict__ critic_b,
    float* __restrict__ out)
{
  __shared__ __align__(16) short pb[16 * PSTR2];   // P bf16 (unnormalized)
  __shared__ __align__(16) float s2s[1024];
  __shared__ float saw[64 * 16];
  __shared__ float scw[64];
  __shared__ float sab[16];
  __shared__ float denom[16];
  __shared__ float emb[16][65];
  int tid = threadIdx.x;
  int b = blockIdx.y;
  int i0 = blockIdx.x * 16;

  for (int j = tid; j < 1024; j += 256) s2s[j] = s2[b * 1024 + j];
  for (int idx2 = tid; idx2 < 64 * 16; idx2 += 256) saw[idx2] = actor_w[idx2];
  if (tid < 64) scw[tid] = critic_w[tid];
  if (tid < 16) sab[tid] = actor_b[tid];
  __syncthreads();

  // Phase A: adj as int4 -> 64-bit register mask; 2 passes, P stored bf16
  {
    int il = tid >> 4, r = tid & 15;
    int i = i0 + il;
    float s1i = s1[b * 1024 + i];
    const int* arow = adj + ((long)(b * 1024 + i)) * 1024;
    unsigned long long amask = 0ull;
    float m = -3.0e38f;
    #pragma unroll
    for (int jj = 0; jj < 16; ++jj) {
      int j0 = jj * 64 + r * 4;
      int4 a4 = *(const int4*)&arow[j0];
      float4 sv = *(const float4*)&s2s[j0];
      float e0 = s1i + sv.x; e0 = (e0 > 0.f) ? e0 : 0.2f * e0;
      float e1 = s1i + sv.y; e1 = (e1 > 0.f) ? e1 : 0.2f * e1;
      float e2 = s1i + sv.z; e2 = (e2 > 0.f) ? e2 : 0.2f * e2;
      float e3 = s1i + sv.w; e3 = (e3 > 0.f) ? e3 : 0.2f * e3;
      if (a4.x > 0) { m = fmaxf(m, e0); amask |= 1ull << (jj * 4 + 0); }
      if (a4.y > 0) { m = fmaxf(m, e1); amask |= 1ull << (jj * 4 + 1); }
      if (a4.z > 0) { m = fmaxf(m, e2); amask |= 1ull << (jj * 4 + 2); }
      if (a4.w > 0) { m = fmaxf(m, e3); amask |= 1ull << (jj * 4 + 3); }
    }
    #pragma unroll
    for (int w = 1; w < 16; w <<= 1) m = fmaxf(m, __shfl_xor(m, w));
    float sum = 0.f;
    short* prow = &pb[il * PSTR2];
    #pragma unroll
    for (int jj = 0; jj < 16; ++jj) {
      int j0 = jj * 64 + r * 4;
      float4 sv = *(const float4*)&s2s[j0];
      float e0 = s1i + sv.x; e0 = (e0 > 0.f) ? e0 : 0.2f * e0;
      float e1 = s1i + sv.y; e1 = (e1 > 0.f) ? e1 : 0.2f * e1;
      float e2 = s1i + sv.z; e2 = (e2 > 0.f) ? e2 : 0.2f * e2;
      float e3 = s1i + sv.w; e3 = (e3 > 0.f) ? e3 : 0.2f * e3;
      float p0 = ((amask >> (jj * 4 + 0)) & 1ull) ? __expf(e0 - m) : 0.f;
      float p1 = ((amask >> (jj * 4 + 1)) & 1ull) ? __expf(e1 - m) : 0.f;
      float p2 = ((amask >> (jj * 4 + 2)) & 1ull) ? __expf(e2 - m) : 0.f;
      float p3 = ((amask >> (jj * 4 + 3)) & 1ull) ? __expf(e3 - m) : 0.f;
      sum += (p0 + p1) + (p2 + p3);
      short4v st;
      st[0] = f32_to_bf16_bits(p0); st[1] = f32_to_bf16_bits(p1);
      st[2] = f32_to_bf16_bits(p2); st[3] = f32_to_bf16_bits(p3);
      *(short4v*)&prow[j0] = st;
    }
    #pragma unroll
    for (int w = 1; w < 16; w <<= 1) sum += __shfl_xor(sum, w);
    if (r == 0) denom[il] = sum;
  }
  __syncthreads();

  // Phase B: h'[16,64] = P[16,1024] @ Wh[1024,64] via MFMA (wave = 16-col slice)
  {
    int lane = tid & 63, wv = tid >> 6, g = lane >> 4, colr = lane & 15;
    const short* Wcol = Whb + ((long)b * 64 + wv * 16 + colr) * 1024;
    const short* prow = &pb[colr * PSTR2];
    f32x4 acc = {0.f, 0.f, 0.f, 0.f};
    #pragma unroll
    for (int ks = 0; ks < 32; ++ks) {
      short8 af = *(const short8*)&prow[ks * 32 + g * 8];
      short8 bf = *(const short8*)&Wcol[ks * 32 + g * 8];
      acc = __builtin_amdgcn_mfma_f32_16x16x32_bf16(af, bf, acc, 0, 0, 0);
    }
    #pragma unroll
    for (int rr = 0; rr < 4; ++rr) {
      int row = g * 4 + rr;
      float v = acc[rr] / denom[row];
      v = (v > 0.f) ? v : expm1f(v);
      emb[row][wv * 16 + colr] = v;
    }
  }
  __syncthreads();

  // heads
  {
    int il = tid >> 4, na = tid & 15;
    float accl = sab[na];
    #pragma unroll
    for (int d = 0; d < 64; ++d) accl += emb[il][d] * saw[d * 16 + na];
    out[((long)(b * 1024 + i0 + il)) * 16 + na] = accl;
  }
  if (tid < 16) {
    float v = critic_b[0];
    #pragma unroll
    for (int d = 0; d < 64; ++d) v += emb[tid][d] * scw[d];
    out[131072 + b * 1024 + i0 + tid] = v;
  }
}

extern "C" void kernel_launch(void* const* d_in, const int* in_sizes, int n_in,
                              void* d_out, int out_size, void* d_ws, size_t ws_size,
                              hipStream_t stream)
{
  const float* obs = (const float*)d_in[0];
  const int*   adj = (const int*)d_in[1];
  const float* c1w = (const float*)d_in[2];
  const float* c1b = (const float*)d_in[3];
  const float* c2w = (const float*)d_in[4];
  const float* c2b = (const float*)d_in[5];
  const float* W   = (const float*)d_in[6];
  const float* a1  = (const float*)d_in[7];
  const float* a2  = (const float*)d_in[8];
  const float* aw  = (const float*)d_in[9];
  const float* ab  = (const float*)d_in[10];
  const float* cw  = (const float*)d_in[11];
  const float* cb  = (const float*)d_in[12];
  float* out = (float*)d_out;
  float* ws = (float*)d_ws;

  short* Whb = (short*)ws;                 // [8][64][1024] bf16 = 1 MB
  float* s1  = ws + 262144;                // 8192 f32
  float* s2  = s1 + 8192;                  // 8192 f32
  short* Wt  = (short*)(s2 + 8192);        // 64*1568 bf16

  hipLaunchKernelGGL(wt_prep, dim3((1568 * 64 + 255) / 256), dim3(256), 0, stream, W, Wt);
  hipLaunchKernelGGL(cnn_gemm_kernel, dim3(1024), dim3(256), 0, stream,
                     obs, c1w, c1b, c2w, c2b, Wt, a1, a2, Whb, s1, s2);
  hipLaunchKernelGGL(gat_kernel, dim3(64, 8), dim3(256), 0, stream,
                     adj, Whb, s1, s2, aw, ab, cw, cb, out);
}